// Round 6
// baseline (191.776 us; speedup 1.0000x reference)
//
#include <hip/hip_runtime.h>

// deepSNN forward, layer_idx=3 path, fp32 exact, element-sparse conv2.
// x:(20,6,160,160) w1:(30,6,4,4) w2:(250,30,3,3) w3:(200,250,3,3)
// pipeline: pad2->conv1->fire(1)->pool2x2 -> pad2->conv2->fire(1)->pool3x3
//           -> pad2->conv3->fire(25) -> out = [spk | pot] (2 x 20*200*29*29 fp32)
//
// r5 post-mortem: v_pk_fma_f32 is NOT 2x on CDNA4 (157.3 TF = scalar rate);
// conv1 floor ~26us VALU-busy. Hidden hog was conv2: 60.5k waves paying full
// fixed cost for 4 outputs/thread (~95us by subtraction). r6: conv2 reshaped
// to 540 blocks — stage 5x84 mask band once, each wave owns 64 ocs and slides
// all 27 pw windows over it. conv1: occupancy 4 blocks/CU + div-free staging.

#define OUT_HALF 3364000  // 20*200*29*29
#define MASK_PLANE 128000 // 20*80*80

typedef float v2f __attribute__((ext_vector_type(2)));

// ---------------- w2 transpose: w2[oc][ck] -> w2t[ck][oc]; also zero flags2
__global__ void k_transpose(const float* __restrict__ w, float* __restrict__ wt,
                            int OC, int CK, unsigned int* zp, int zn) {
    if (blockIdx.x == 0 && zp) {
        for (int i = threadIdx.x; i < zn; i += 256) zp[i] = 0u;
    }
    int idx = blockIdx.x * 256 + threadIdx.x;
    if (idx < OC * CK) {
        int oc = idx / CK, ck = idx % CK;
        wt[ck * OC + oc] = w[idx];
    }
}

// ---------------- conv1(4x4) + fire(1.0) + pool2x2 -> mask1 u32, 2 planes
// block: (t, 5 row-tiles, 5 col-tiles, 2 oc-halves), 256 thr = one pool cell.
// mask1[h*MASK_PLANE + (t*80+r)*80+c] bits 0..14 = spikes of oc h*15..h*15+14.
// Input LDS layout: [c][row][perm(col)], perm = col/2 + (col&1)*18 -> window
// reads hit 2 lanes/bank (free). Weights: wave-uniform global float4 loads
// (scalar pipe). Staging is div-free (incremental channel/row carry).
__global__ __launch_bounds__(256, 4) void k_conv1(const float* __restrict__ x,
                                                  const float* __restrict__ w1,
                                                  unsigned int* __restrict__ mask1) {
    __shared__ float in_lds[6 * 35 * 36];  // 30240 B

    int b = blockIdx.x;
    int h = b & 1;     b >>= 1;  // oc half: 0 -> oc 0..14, 1 -> oc 15..29
    int colt = b % 5;  b /= 5;
    int rowt = b % 5;  b /= 5;
    int t = b;
    int ph0 = rowt * 16, pw0 = colt * 16;
    int i0 = 2 * ph0, j0 = 2 * pw0;  // padded-164 coords of tile conv origin
    int tid = threadIdx.x;

    // stage 210 rows (c*35+rr) x 35 cols; thread -> (group g, col), row = g+7k
    {
        int g = tid / 35;
        int col = tid - g * 35;
        if (g < 7) {
            int perm = (col >> 1) + (col & 1) * 18;
            int gc = j0 + col - 2;
            bool cok = (unsigned)gc < 160u;
            int c = 0, rr = g;
            const float* xt = x + (size_t)t * 6 * 160 * 160 + gc;
#pragma unroll 1
            for (int k = 0; k < 30; ++k) {
                int gr = i0 + rr - 2;
                float v = 0.f;
                if (cok && (unsigned)gr < 160u)
                    v = xt[(c * 160 + gr) * 160];
                in_lds[c * 1260 + rr * 36 + perm] = v;
                rr += 7;
                if (rr >= 35) { rr -= 35; ++c; }
            }
        }
    }
    __syncthreads();

    int pw_l = tid & 15, ph_l = tid >> 4;
    int rb = 2 * ph_l;

    v2f acc01[15], acc23[15];  // positions (0,0),(0,1) and (1,0),(1,1)
#pragma unroll
    for (int o = 0; o < 15; ++o) {
        acc01[o] = (v2f)(0.f);
        acc23[o] = (v2f)(0.f);
    }

    // weights for this half: w1[(h*15+o)][c][kh][kw], float4 per (o,c,kh)
    const float4* wq = (const float4*)w1 + h * 15 * 24;

#pragma unroll 1
    for (int c = 0; c < 6; ++c) {
        // window cols cb..cb+4 (cb=2*pw_l): permuted offsets 0,18,1,19,2
        const float* pl = &in_lds[c * 1260 + rb * 36 + pw_l];
        float q[5][5];
#pragma unroll
        for (int r = 0; r < 5; ++r) {
            const float* pr = pl + r * 36;
            q[r][0] = pr[0];  q[r][1] = pr[18]; q[r][2] = pr[1];
            q[r][3] = pr[19]; q[r][4] = pr[2];
        }
        v2f p[5][4];  // p[r][k] = {in[r][k], in[r][k+1]}
#pragma unroll
        for (int r = 0; r < 5; ++r)
#pragma unroll
            for (int k = 0; k < 4; ++k) {
                p[r][k].x = q[r][k];
                p[r][k].y = q[r][k + 1];
            }
#pragma unroll
        for (int o = 0; o < 15; ++o) {
            const float4* wp = wq + o * 24 + c * 4;
#pragma unroll
            for (int kh = 0; kh < 4; ++kh) {
                float4 wv = wp[kh];  // uniform -> scalar regs
                v2f w0 = {wv.x, wv.x}, w1v = {wv.y, wv.y};
                v2f w2v = {wv.z, wv.z}, w3v = {wv.w, wv.w};
                acc01[o] += p[kh][0] * w0;   acc23[o] += p[kh + 1][0] * w0;
                acc01[o] += p[kh][1] * w1v;  acc23[o] += p[kh + 1][1] * w1v;
                acc01[o] += p[kh][2] * w2v;  acc23[o] += p[kh + 1][2] * w2v;
                acc01[o] += p[kh][3] * w3v;  acc23[o] += p[kh + 1][3] * w3v;
            }
        }
    }

    unsigned int msk = 0;
#pragma unroll
    for (int o = 0; o < 15; ++o) {
        bool s = acc01[o].x > 1.f || acc01[o].y > 1.f ||
                 acc23[o].x > 1.f || acc23[o].y > 1.f;
        if (s) msk |= 1u << o;
    }
    mask1[h * MASK_PLANE + (t * 80 + ph0 + ph_l) * 80 + pw0 + pw_l] = msk;
}

// ---------------- sparse conv2(3x3) + fire(1.0) + pool3x3 -> pool2 u8
// block: (t, ph) = 540 blocks, 256 thr = 4 waves; wave w owns ocs w*64..w*64+63
// (250 valid). Stage the 5x84 mask row-band once; each wave slides pw=0..26,
// scanning the 5x5 word window (broadcast LDS reads) and stamping weights for
// each set spike bit: <=9 lane-coalesced w2t loads + FMAs per spike. Exact.
__global__ __launch_bounds__(256) void k_conv2(const unsigned int* __restrict__ mask1,
                                               const float* __restrict__ w2t,
                                               unsigned char* __restrict__ pool2,
                                               unsigned int* __restrict__ flags2) {
    __shared__ unsigned int m_lds[5 * 84];  // rows 3ph-2..3ph+2, cols -2..81
    __shared__ int f2;

    int b = blockIdx.x;
    int ph = b % 27;
    int t = b / 27;
    int tid = threadIdx.x;
    int ocl = tid & 63, wv = tid >> 6;
    int r0 = 3 * ph - 2;

    if (tid == 0) f2 = 0;
    for (int idx = tid; idx < 420; idx += 256) {
        int r = idx / 84, col = idx % 84;
        int gr = r0 + r, gc = col - 2;
        unsigned int v = 0;
        if ((unsigned)gr < 80u && (unsigned)gc < 80u) {
            int i2 = (t * 80 + gr) * 80 + gc;
            v = mask1[i2] | (mask1[MASK_PLANE + i2] << 15);
        }
        m_lds[idx] = v;
    }
    __syncthreads();

    int oc = wv * 64 + ocl;  // 0..255; stray 250..255 reads land in pad region
    const float* wb = w2t + oc;
    unsigned char* prow = pool2 + ((t * 250 + oc) * 27 + ph) * 27;
    bool valid = oc < 250;

#pragma unroll 1
    for (int pw = 0; pw < 27; ++pw) {
        float acc[3][3];
#pragma unroll
        for (int i = 0; i < 3; ++i)
#pragma unroll
            for (int j = 0; j < 3; ++j) acc[i][j] = 0.f;

        int c0 = 3 * pw;  // lds col of window start (global col 3pw-2)
#pragma unroll
        for (int dr = 0; dr < 5; ++dr) {
#pragma unroll
            for (int ds = 0; ds < 5; ++ds) {
                unsigned int m = m_lds[dr * 84 + c0 + ds];
                while (m) {
                    int c = __builtin_ctz(m);
                    m &= m - 1;
                    const float* wc = wb + c * (9 * 250);
#pragma unroll
                    for (int i = 0; i < 3; ++i) {
                        if (dr - i >= 0 && dr - i <= 2) {
#pragma unroll
                            for (int j = 0; j < 3; ++j) {
                                if (ds - j >= 0 && ds - j <= 2)
                                    acc[i][j] +=
                                        wc[((dr - i) * 3 + (ds - j)) * 250];
                            }
                        }
                    }
                }
            }
        }

        bool s = false;
#pragma unroll
        for (int i = 0; i < 3; ++i)
#pragma unroll
            for (int j = 0; j < 3; ++j) s = s || (acc[i][j] > 1.f);

        if (valid) {
            prow[pw] = s ? (unsigned char)1 : (unsigned char)0;
            if (s) f2 = 1;  // same-value LDS store, race-safe
        }
    }
    __syncthreads();
    if (tid == 0 && f2) flags2[t * 27 + ph] = 1u;
}

// ---------------- conv3(3x3) + fire(25.0) -> out [spk|pot] (20,200,29,29) x2
// block: (t, 5 oc-groups of 40, 15 row-pairs), 320 thr = 40oc x 8 col-tiles(4)
// Early-out via flags2 rows r0-2..r0+1 -> coalesced zero-fill. Dense path
// stages w3 directly (uncoalesced but never executed when pool2 is empty).
__global__ __launch_bounds__(320) void k_conv3(const unsigned char* __restrict__ pool2,
                                               const float* __restrict__ w3,
                                               float* __restrict__ out,
                                               const unsigned int* __restrict__ flags2) {
    __shared__ float w_lds[25 * 9 * 40];   // 9000 floats, [ck_local][ocl]
    __shared__ float in_lds[25 * 4 * 34];  // 3400 floats, [cl][r][col]

    int b = blockIdx.x;
    int rb = b % 15;  b /= 15;
    int ocg = b % 5;  b /= 5;
    int t = b;
    int oc0 = ocg * 40;
    int r0 = 2 * rb;  // output rows r0, r0+1
    int tid = threadIdx.x;
    int ocl = tid % 40, ct = tid / 40;  // ct in [0,8)

    // receptive field: pool2 rows r0-2..r0+1
    {
        unsigned int f = 0;
        int rlo = r0 - 2; if (rlo < 0) rlo = 0;
        int rhi = r0 + 1; if (rhi > 26) rhi = 26;
        for (int r = rlo; r <= rhi; ++r) f |= flags2[t * 27 + r];
        if (f == 0) {
            // exact zeros, coalesced: rows r0..r0+nrows-1, all 29 cols, 40 ocs
            int nrows = (r0 + 1 < 29) ? 2 : 1;
            int stride = 29 * nrows;
            int cnt = 40 * stride;
            for (int idx = tid; idx < cnt; idx += 320) {
                int o = idx / stride, rem = idx % stride;
                size_t base = (size_t)((t * 200 + oc0 + o) * 29 + r0) * 29 + rem;
                out[base] = 0.f;
                out[OUT_HALF + base] = 0.f;
            }
            return;
        }
    }

    float acc[2][4];
#pragma unroll
    for (int i = 0; i < 2; ++i)
#pragma unroll
        for (int j = 0; j < 4; ++j) acc[i][j] = 0.f;

    for (int chn = 0; chn < 10; ++chn) {  // channel chunks of 25
        int cc0 = chn * 25;
        for (int idx = tid; idx < 25 * 9 * 40; idx += 320) {
            int o = idx % 40, ck = idx / 40;         // ck in [0,225)
            int ckg = cc0 * 9 + ck;                  // global (c,kh,kw) index
            w_lds[idx] = w3[(size_t)(oc0 + o) * 2250 + ckg];
        }
        for (int idx = tid; idx < 25 * 4 * 34; idx += 320) {
            int col = idx % 34;
            int rem = idx / 34;
            int r = rem & 3, cl = rem >> 2;
            int gr = r0 + r - 2, gc = col - 2;
            float v = 0.f;
            if ((unsigned)gr < 27u && (unsigned)gc < 27u)
                v = (float)pool2[((t * 250 + cc0 + cl) * 27 + gr) * 27 + gc];
            in_lds[idx] = v;
        }
        __syncthreads();

        for (int cl = 0; cl < 25; ++cl) {
            float in[4][6];
#pragma unroll
            for (int r = 0; r < 4; ++r)
#pragma unroll
                for (int j = 0; j < 6; ++j)
                    in[r][j] = in_lds[(cl * 4 + r) * 34 + ct * 4 + j];
            const float* wp = &w_lds[cl * 360 + ocl];
#pragma unroll
            for (int k = 0; k < 9; ++k) {
                float w = wp[k * 40];
                int kh = k / 3, kw = k % 3;
#pragma unroll
                for (int i = 0; i < 2; ++i)
#pragma unroll
                    for (int j = 0; j < 4; ++j)
                        acc[i][j] += in[i + kh][j + kw] * w;
            }
        }
        __syncthreads();
    }

    {
        int oc = oc0 + ocl;  // always < 200
#pragma unroll
        for (int i = 0; i < 2; ++i) {
            int r = r0 + i;
            if (r < 29) {
#pragma unroll
                for (int j = 0; j < 4; ++j) {
                    int col = ct * 4 + j;
                    if (col < 29) {
                        float pot = acc[i][j];
                        bool s = pot > 25.f;
                        size_t base = ((size_t)((t * 200 + oc) * 29 + r)) * 29 + col;
                        out[base] = s ? 1.f : 0.f;
                        out[OUT_HALF + base] = s ? pot : 0.f;
                    }
                }
            }
        }
    }
}

extern "C" void kernel_launch(void* const* d_in, const int* in_sizes, int n_in,
                              void* d_out, int out_size, void* d_ws, size_t ws_size,
                              hipStream_t stream) {
    const float* x  = (const float*)d_in[0];
    const float* w1 = (const float*)d_in[1];
    const float* w2 = (const float*)d_in[2];
    const float* w3 = (const float*)d_in[3];
    float* out = (float*)d_out;

    // workspace layout (bytes):
    //   mask1 u32: [0, 1,024,000)            2 planes x 20*80*80
    //   pool2 u8 : [1,024,000, 4,669,000)    20*250*27*27
    //   w2t  f32 : [4,669,056, +270,000)     270x250  (ends 4,939,056)
    //   pad      : [4,939,056, 4,943,872)    absorbs conv2 stray oc reads
    //   flags2   : [4,943,872, +2,160)       u32[20*27]
    unsigned int* mask1 = (unsigned int*)d_ws;
    unsigned char* pool2 = (unsigned char*)d_ws + 1024000;
    float* w2t = (float*)((char*)d_ws + 4669056);
    unsigned int* flags2 = (unsigned int*)((char*)d_ws + 4943872);

    k_transpose<<<(250 * 270 + 255) / 256, 256, 0, stream>>>(w2, w2t, 250, 270,
                                                             flags2, 540);
    k_conv1<<<20 * 5 * 5 * 2, 256, 0, stream>>>(x, w1, mask1);
    k_conv2<<<20 * 27, 256, 0, stream>>>(mask1, w2t, pool2, flags2);
    k_conv3<<<20 * 5 * 15, 320, 0, stream>>>(pool2, w3, out, flags2);
}

// Round 7
// 184.244 us; speedup vs baseline: 1.0409x; 1.0409x over previous
//
#include <hip/hip_runtime.h>

// deepSNN forward, layer_idx=3 path, fp32 exact, element-sparse conv2.
// x:(20,6,160,160) w1:(30,6,4,4) w2:(250,30,3,3) w3:(200,250,3,3)
// pipeline: pad2->conv1->fire(1)->pool2x2 -> pad2->conv2->fire(1)->pool3x3
//           -> pad2->conv3->fire(25) -> out = [spk | pot] (2 x 20*200*29*29 fp32)
//
// r6 post-mortem: conv2 was HBM-WRITE-bound — 64 byte-stores/wave at stride
// 729 B dirtied 56.7 MB of HBM writebacks for a 3.6 MB tensor (77 us ~= 56.7MB
// / 767 GB/s). r7: pool2 stored as per-wave __ballot u64 bitmask (one 8B store
// per wave per pw; 466 KB total). conv1 reverted to the r5 version (measured
// 48 us; r6's staging tweak regressed it). conv3 unpacks the bitmask in its
// (never-executed on this input) dense path.

#define OUT_HALF 3364000  // 20*200*29*29
#define MASK_PLANE 128000 // 20*80*80

typedef float v2f __attribute__((ext_vector_type(2)));

// ---------------- w2 transpose: w2[oc][ck] -> w2t[ck][oc]; also zero flags2
__global__ void k_transpose(const float* __restrict__ w, float* __restrict__ wt,
                            int OC, int CK, unsigned int* zp, int zn) {
    if (blockIdx.x == 0 && zp) {
        for (int i = threadIdx.x; i < zn; i += 256) zp[i] = 0u;
    }
    int idx = blockIdx.x * 256 + threadIdx.x;
    if (idx < OC * CK) {
        int oc = idx / CK, ck = idx % CK;
        wt[ck * OC + oc] = w[idx];
    }
}

// ---------------- conv1(4x4) + fire(1.0) + pool2x2 -> mask1 u32, 2 planes
// block: (t, 5 row-tiles, 5 col-tiles, 2 oc-halves), 256 thr = one pool cell.
// mask1[h*MASK_PLANE + (t*80+r)*80+c] bits 0..14 = spikes of oc h*15..h*15+14.
// Input LDS layout: [c][row][perm(col)], perm = col/2 + (col&1)*18 -> window
// reads hit 2 lanes/bank (free). Weights: wave-uniform global float4 loads
// (scalar pipe), never touch LDS.  [r5 version, measured 48 us]
__global__ __launch_bounds__(256, 3) void k_conv1(const float* __restrict__ x,
                                                  const float* __restrict__ w1,
                                                  unsigned int* __restrict__ mask1) {
    __shared__ float in_lds[6 * 35 * 36];  // 30240 B

    int b = blockIdx.x;
    int h = b & 1;     b >>= 1;  // oc half: 0 -> oc 0..14, 1 -> oc 15..29
    int colt = b % 5;  b /= 5;
    int rowt = b % 5;  b /= 5;
    int t = b;
    int ph0 = rowt * 16, pw0 = colt * 16;
    int i0 = 2 * ph0, j0 = 2 * pw0;  // padded-164 coords of tile conv origin
    int tid = threadIdx.x;

    for (int idx = tid; idx < 6 * 35 * 35; idx += 256) {
        int c = idx / 1225;
        int rem = idx % 1225;
        int r = rem / 35, col = rem % 35;
        int gr = i0 + r - 2, gc = j0 + col - 2;
        float v = 0.f;
        if ((unsigned)gr < 160u && (unsigned)gc < 160u)
            v = x[((t * 6 + c) * 160 + gr) * 160 + gc];
        in_lds[c * 1260 + r * 36 + (col >> 1) + (col & 1) * 18] = v;
    }
    __syncthreads();

    int pw_l = tid & 15, ph_l = tid >> 4;
    int rb = 2 * ph_l;

    v2f acc01[15], acc23[15];  // positions (0,0),(0,1) and (1,0),(1,1)
#pragma unroll
    for (int o = 0; o < 15; ++o) {
        acc01[o] = (v2f)(0.f);
        acc23[o] = (v2f)(0.f);
    }

    // weights for this half: w1[(h*15+o)][c][kh][kw], float4 per (o,c,kh)
    const float4* wq = (const float4*)w1 + h * 15 * 24;

#pragma unroll 1
    for (int c = 0; c < 6; ++c) {
        // window cols cb..cb+4 (cb=2*pw_l): permuted offsets 0,18,1,19,2
        const float* pl = &in_lds[c * 1260 + rb * 36 + pw_l];
        float q[5][5];
#pragma unroll
        for (int r = 0; r < 5; ++r) {
            const float* pr = pl + r * 36;
            q[r][0] = pr[0];  q[r][1] = pr[18]; q[r][2] = pr[1];
            q[r][3] = pr[19]; q[r][4] = pr[2];
        }
        v2f p[5][4];  // p[r][k] = {in[r][k], in[r][k+1]}
#pragma unroll
        for (int r = 0; r < 5; ++r)
#pragma unroll
            for (int k = 0; k < 4; ++k) {
                p[r][k].x = q[r][k];
                p[r][k].y = q[r][k + 1];
            }
#pragma unroll
        for (int o = 0; o < 15; ++o) {
            const float4* wp = wq + o * 24 + c * 4;
#pragma unroll
            for (int kh = 0; kh < 4; ++kh) {
                float4 wv = wp[kh];  // uniform -> scalar regs
                v2f w0 = {wv.x, wv.x}, w1v = {wv.y, wv.y};
                v2f w2v = {wv.z, wv.z}, w3v = {wv.w, wv.w};
                acc01[o] += p[kh][0] * w0;   acc23[o] += p[kh + 1][0] * w0;
                acc01[o] += p[kh][1] * w1v;  acc23[o] += p[kh + 1][1] * w1v;
                acc01[o] += p[kh][2] * w2v;  acc23[o] += p[kh + 1][2] * w2v;
                acc01[o] += p[kh][3] * w3v;  acc23[o] += p[kh + 1][3] * w3v;
            }
        }
    }

    unsigned int msk = 0;
#pragma unroll
    for (int o = 0; o < 15; ++o) {
        bool s = acc01[o].x > 1.f || acc01[o].y > 1.f ||
                 acc23[o].x > 1.f || acc23[o].y > 1.f;
        if (s) msk |= 1u << o;
    }
    mask1[h * MASK_PLANE + (t * 80 + ph0 + ph_l) * 80 + pw0 + pw_l] = msk;
}

// ---------------- sparse conv2(3x3) + fire(1.0) + pool3x3 -> pool2m ballot
// block: (t, ph) = 540 blocks, 256 thr = 4 waves; wave w owns ocs w*64..+63.
// Stage the 5x84 mask row-band once; each wave slides pw=0..26 scanning the
// 5x5 word window (broadcast LDS reads), stamping weights per spike bit
// (<=9 lane-coalesced w2t loads + FMAs). Output: one __ballot u64 per
// (t,ph,pw,wave) — 466 KB total, no scattered byte stores. Exact.
__global__ __launch_bounds__(256) void k_conv2(const unsigned int* __restrict__ mask1,
                                               const float* __restrict__ w2t,
                                               unsigned long long* __restrict__ pool2m,
                                               unsigned int* __restrict__ flags2) {
    __shared__ unsigned int m_lds[5 * 84];  // rows 3ph-2..3ph+2, cols -2..81
    __shared__ int f2;

    int b = blockIdx.x;
    int ph = b % 27;
    int t = b / 27;
    int tid = threadIdx.x;
    int ocl = tid & 63, wv = tid >> 6;
    int r0 = 3 * ph - 2;

    if (tid == 0) f2 = 0;
    for (int idx = tid; idx < 420; idx += 256) {
        int r = idx / 84, col = idx % 84;
        int gr = r0 + r, gc = col - 2;
        unsigned int v = 0;
        if ((unsigned)gr < 80u && (unsigned)gc < 80u) {
            int i2 = (t * 80 + gr) * 80 + gc;
            v = mask1[i2] | (mask1[MASK_PLANE + i2] << 15);
        }
        m_lds[idx] = v;
    }
    __syncthreads();

    int oc = wv * 64 + ocl;  // 0..255; stray 250..255 reads stay within pad
    const float* wb = w2t + oc;
    bool valid = oc < 250;
    unsigned long long* prow = pool2m + ((t * 27 + ph) * 27) * 4 + wv;

#pragma unroll 1
    for (int pw = 0; pw < 27; ++pw) {
        float acc[3][3];
#pragma unroll
        for (int i = 0; i < 3; ++i)
#pragma unroll
            for (int j = 0; j < 3; ++j) acc[i][j] = 0.f;

        int c0 = 3 * pw;  // lds col of window start (global col 3pw-2)
#pragma unroll
        for (int dr = 0; dr < 5; ++dr) {
#pragma unroll
            for (int ds = 0; ds < 5; ++ds) {
                unsigned int m = m_lds[dr * 84 + c0 + ds];
                while (m) {  // wave-uniform (broadcast word)
                    int c = __builtin_ctz(m);
                    m &= m - 1;
                    const float* wc = wb + c * (9 * 250);
#pragma unroll
                    for (int i = 0; i < 3; ++i) {
                        if (dr - i >= 0 && dr - i <= 2) {
#pragma unroll
                            for (int j = 0; j < 3; ++j) {
                                if (ds - j >= 0 && ds - j <= 2)
                                    acc[i][j] +=
                                        wc[((dr - i) * 3 + (ds - j)) * 250];
                            }
                        }
                    }
                }
            }
        }

        bool s = false;
#pragma unroll
        for (int i = 0; i < 3; ++i)
#pragma unroll
            for (int j = 0; j < 3; ++j) s = s || (acc[i][j] > 1.f);

        unsigned long long blt = __ballot(s && valid);
        if (ocl == 0) prow[pw * 4] = blt;
        if (blt) f2 = 1;  // same-value LDS store, race-safe
    }
    __syncthreads();
    if (tid == 0 && f2) flags2[t * 27 + ph] = 1u;
}

// ---------------- conv3(3x3) + fire(25.0) -> out [spk|pot] (20,200,29,29) x2
// block: (t, 5 oc-groups of 40, 15 row-pairs), 320 thr = 40oc x 8 col-tiles(4)
// Early-out via flags2 rows r0-2..r0+1 -> coalesced zero-fill. Dense path
// unpacks pool2m bits (never executed when pool2 is empty; kept for
// correctness on arbitrary inputs).
__global__ __launch_bounds__(320) void k_conv3(const unsigned long long* __restrict__ pool2m,
                                               const float* __restrict__ w3,
                                               float* __restrict__ out,
                                               const unsigned int* __restrict__ flags2) {
    __shared__ float w_lds[25 * 9 * 40];   // 9000 floats, [ck_local][ocl]
    __shared__ float in_lds[25 * 4 * 34];  // 3400 floats, [cl][r][col]

    int b = blockIdx.x;
    int rb = b % 15;  b /= 15;
    int ocg = b % 5;  b /= 5;
    int t = b;
    int oc0 = ocg * 40;
    int r0 = 2 * rb;  // output rows r0, r0+1
    int tid = threadIdx.x;
    int ocl = tid % 40, ct = tid / 40;  // ct in [0,8)

    // receptive field: pool2 rows r0-2..r0+1
    {
        unsigned int f = 0;
        int rlo = r0 - 2; if (rlo < 0) rlo = 0;
        int rhi = r0 + 1; if (rhi > 26) rhi = 26;
        for (int r = rlo; r <= rhi; ++r) f |= flags2[t * 27 + r];
        if (f == 0) {
            // exact zeros, coalesced: rows r0..r0+nrows-1, all 29 cols, 40 ocs
            int nrows = (r0 + 1 < 29) ? 2 : 1;
            int stride = 29 * nrows;
            int cnt = 40 * stride;
            for (int idx = tid; idx < cnt; idx += 320) {
                int o = idx / stride, rem = idx % stride;
                size_t base = (size_t)((t * 200 + oc0 + o) * 29 + r0) * 29 + rem;
                out[base] = 0.f;
                out[OUT_HALF + base] = 0.f;
            }
            return;
        }
    }

    float acc[2][4];
#pragma unroll
    for (int i = 0; i < 2; ++i)
#pragma unroll
        for (int j = 0; j < 4; ++j) acc[i][j] = 0.f;

    for (int chn = 0; chn < 10; ++chn) {  // channel chunks of 25
        int cc0 = chn * 25;
        for (int idx = tid; idx < 25 * 9 * 40; idx += 320) {
            int o = idx % 40, ck = idx / 40;         // ck in [0,225)
            int ckg = cc0 * 9 + ck;                  // global (c,kh,kw) index
            w_lds[idx] = w3[(size_t)(oc0 + o) * 2250 + ckg];
        }
        for (int idx = tid; idx < 25 * 4 * 34; idx += 320) {
            int col = idx % 34;
            int rem = idx / 34;
            int r = rem & 3, cl = rem >> 2;
            int gr = r0 + r - 2, gc = col - 2;
            float v = 0.f;
            if ((unsigned)gr < 27u && (unsigned)gc < 27u) {
                int c = cc0 + cl;
                unsigned long long wbits =
                    pool2m[((t * 27 + gr) * 27 + gc) * 4 + (c >> 6)];
                v = (float)((wbits >> (c & 63)) & 1ull);
            }
            in_lds[idx] = v;
        }
        __syncthreads();

        for (int cl = 0; cl < 25; ++cl) {
            float in[4][6];
#pragma unroll
            for (int r = 0; r < 4; ++r)
#pragma unroll
                for (int j = 0; j < 6; ++j)
                    in[r][j] = in_lds[(cl * 4 + r) * 34 + ct * 4 + j];
            const float* wp = &w_lds[cl * 360 + ocl];
#pragma unroll
            for (int k = 0; k < 9; ++k) {
                float w = wp[k * 40];
                int kh = k / 3, kw = k % 3;
#pragma unroll
                for (int i = 0; i < 2; ++i)
#pragma unroll
                    for (int j = 0; j < 4; ++j)
                        acc[i][j] += in[i + kh][j + kw] * w;
            }
        }
        __syncthreads();
    }

    {
        int oc = oc0 + ocl;  // always < 200
#pragma unroll
        for (int i = 0; i < 2; ++i) {
            int r = r0 + i;
            if (r < 29) {
#pragma unroll
                for (int j = 0; j < 4; ++j) {
                    int col = ct * 4 + j;
                    if (col < 29) {
                        float pot = acc[i][j];
                        bool s = pot > 25.f;
                        size_t base = ((size_t)((t * 200 + oc) * 29 + r)) * 29 + col;
                        out[base] = s ? 1.f : 0.f;
                        out[OUT_HALF + base] = s ? pot : 0.f;
                    }
                }
            }
        }
    }
}

extern "C" void kernel_launch(void* const* d_in, const int* in_sizes, int n_in,
                              void* d_out, int out_size, void* d_ws, size_t ws_size,
                              hipStream_t stream) {
    const float* x  = (const float*)d_in[0];
    const float* w1 = (const float*)d_in[1];
    const float* w2 = (const float*)d_in[2];
    const float* w3 = (const float*)d_in[3];
    float* out = (float*)d_out;

    // workspace layout (bytes):
    //   mask1  u32: [0, 1,024,000)           2 planes x 20*80*80
    //   pool2m u64: [1,024,000, 1,490,560)   20*27*27*4 x 8B ballot words
    //   w2t    f32: [1,490,560, 1,760,560)   270x250
    //   pad       : [1,760,560, 1,764,672)   absorbs conv2 stray oc reads
    //   flags2    : [1,764,672, +2,160)      u32[20*27]
    unsigned int* mask1 = (unsigned int*)d_ws;
    unsigned long long* pool2m = (unsigned long long*)((char*)d_ws + 1024000);
    float* w2t = (float*)((char*)d_ws + 1490560);
    unsigned int* flags2 = (unsigned int*)((char*)d_ws + 1764672);

    k_transpose<<<(250 * 270 + 255) / 256, 256, 0, stream>>>(w2, w2t, 250, 270,
                                                             flags2, 540);
    k_conv1<<<20 * 5 * 5 * 2, 256, 0, stream>>>(x, w1, mask1);
    k_conv2<<<20 * 27, 256, 0, stream>>>(mask1, w2t, pool2m, flags2);
    k_conv3<<<20 * 5 * 15, 320, 0, stream>>>(pool2m, w3, out, flags2);
}

// Round 8
// 151.541 us; speedup vs baseline: 1.2655x; 1.2158x over previous
//
#include <hip/hip_runtime.h>

// deepSNN forward, layer_idx=3 path, fp32 exact, element-sparse conv2.
// x:(20,6,160,160) w1:(30,6,4,4) w2:(250,30,3,3) w3:(200,250,3,3)
// pipeline: pad2->conv1->fire(1)->pool2x2 -> pad2->conv2->fire(1)->pool3x3
//           -> pad2->conv3->fire(25) -> out = [spk | pot] (2 x 20*200*29*29 fp32)
//
// r7 post-mortem: conv2 latency-bound (VALUBusy 18%, HBM 0.3%): 675 serial
// ds_read->branch chains + per-spike dependent 9-load gathers ~= 160k cyc at
// 2 waves/SIMD = 67us. r8: (a) 25 window words batched into registers (one
// wait, not 25 serial), (b) spike gathers pair-batched (18 independent loads
// per group), (c) 3-way pw split -> 1620 blocks, 6.3 waves/SIMD to hide
// gather latency, (d) w2 transpose folded into the conv1 dispatch.

#define OUT_HALF 3364000  // 20*200*29*29
#define MASK_PLANE 128000 // 20*80*80

typedef float v2f __attribute__((ext_vector_type(2)));

// ---------------- conv1(4x4)+fire(1)+pool2x2 -> mask1 (blocks 0..999)
//                  + w2 transpose + flags2 zero   (blocks 1000..1263)
// conv1 block: (t, 5 row-tiles, 5 col-tiles, 2 oc-halves), 256 thr.
// mask1[h*MASK_PLANE + (t*80+r)*80+c] bits 0..14 = spikes of oc h*15..h*15+14.
// Input LDS layout: [c][row][perm(col)], perm = col/2 + (col&1)*18 -> window
// reads hit 2 lanes/bank (free). Weights: wave-uniform global float4 loads.
__global__ __launch_bounds__(256, 3) void k_conv1(const float* __restrict__ x,
                                                  const float* __restrict__ w1,
                                                  const float* __restrict__ w2,
                                                  float* __restrict__ w2t,
                                                  unsigned int* __restrict__ mask1,
                                                  unsigned int* __restrict__ flags2) {
    if (blockIdx.x >= 1000) {  // transpose part: w2[oc][ck] -> w2t[ck][oc]
        int tb = blockIdx.x - 1000;
        int tid = threadIdx.x;
        if (tb == 0)
            for (int i = tid; i < 540; i += 256) flags2[i] = 0u;
        int idx = tb * 256 + tid;
        if (idx < 67500) {
            int oc = idx / 270, ck = idx % 270;
            w2t[ck * 250 + oc] = w2[idx];
        }
        return;
    }

    __shared__ float in_lds[6 * 35 * 36];  // 30240 B

    int b = blockIdx.x;
    int h = b & 1;     b >>= 1;  // oc half: 0 -> oc 0..14, 1 -> oc 15..29
    int colt = b % 5;  b /= 5;
    int rowt = b % 5;  b /= 5;
    int t = b;
    int ph0 = rowt * 16, pw0 = colt * 16;
    int i0 = 2 * ph0, j0 = 2 * pw0;  // padded-164 coords of tile conv origin
    int tid = threadIdx.x;

    for (int idx = tid; idx < 6 * 35 * 35; idx += 256) {
        int c = idx / 1225;
        int rem = idx % 1225;
        int r = rem / 35, col = rem % 35;
        int gr = i0 + r - 2, gc = j0 + col - 2;
        float v = 0.f;
        if ((unsigned)gr < 160u && (unsigned)gc < 160u)
            v = x[((t * 6 + c) * 160 + gr) * 160 + gc];
        in_lds[c * 1260 + r * 36 + (col >> 1) + (col & 1) * 18] = v;
    }
    __syncthreads();

    int pw_l = tid & 15, ph_l = tid >> 4;
    int rb = 2 * ph_l;

    v2f acc01[15], acc23[15];  // positions (0,0),(0,1) and (1,0),(1,1)
#pragma unroll
    for (int o = 0; o < 15; ++o) {
        acc01[o] = (v2f)(0.f);
        acc23[o] = (v2f)(0.f);
    }

    // weights for this half: w1[(h*15+o)][c][kh][kw], float4 per (o,c,kh)
    const float4* wq = (const float4*)w1 + h * 15 * 24;

#pragma unroll 1
    for (int c = 0; c < 6; ++c) {
        // window cols cb..cb+4 (cb=2*pw_l): permuted offsets 0,18,1,19,2
        const float* pl = &in_lds[c * 1260 + rb * 36 + pw_l];
        float q[5][5];
#pragma unroll
        for (int r = 0; r < 5; ++r) {
            const float* pr = pl + r * 36;
            q[r][0] = pr[0];  q[r][1] = pr[18]; q[r][2] = pr[1];
            q[r][3] = pr[19]; q[r][4] = pr[2];
        }
        v2f p[5][4];  // p[r][k] = {in[r][k], in[r][k+1]}
#pragma unroll
        for (int r = 0; r < 5; ++r)
#pragma unroll
            for (int k = 0; k < 4; ++k) {
                p[r][k].x = q[r][k];
                p[r][k].y = q[r][k + 1];
            }
#pragma unroll
        for (int o = 0; o < 15; ++o) {
            const float4* wp = wq + o * 24 + c * 4;
#pragma unroll
            for (int kh = 0; kh < 4; ++kh) {
                float4 wv = wp[kh];  // uniform -> scalar regs
                v2f w0 = {wv.x, wv.x}, w1v = {wv.y, wv.y};
                v2f w2v = {wv.z, wv.z}, w3v = {wv.w, wv.w};
                acc01[o] += p[kh][0] * w0;   acc23[o] += p[kh + 1][0] * w0;
                acc01[o] += p[kh][1] * w1v;  acc23[o] += p[kh + 1][1] * w1v;
                acc01[o] += p[kh][2] * w2v;  acc23[o] += p[kh + 1][2] * w2v;
                acc01[o] += p[kh][3] * w3v;  acc23[o] += p[kh + 1][3] * w3v;
            }
        }
    }

    unsigned int msk = 0;
#pragma unroll
    for (int o = 0; o < 15; ++o) {
        bool s = acc01[o].x > 1.f || acc01[o].y > 1.f ||
                 acc23[o].x > 1.f || acc23[o].y > 1.f;
        if (s) msk |= 1u << o;
    }
    mask1[h * MASK_PLANE + (t * 80 + ph0 + ph_l) * 80 + pw0 + pw_l] = msk;
}

// ---------------- sparse conv2(3x3) + fire(1.0) + pool3x3 -> pool2m ballot
// block: (t, ph, 3 pw-thirds) = 1620 blocks, 256 thr = 4 waves; wave w owns
// ocs w*64..+63. Stage 5x84 mask band; per pw: 25 window words batched into
// registers (independent ds_reads), spikes processed two-at-a-time with 18
// independent weight loads per group. Output: __ballot u64 per (pw,wave).
__global__ __launch_bounds__(256) void k_conv2(const unsigned int* __restrict__ mask1,
                                               const float* __restrict__ w2t,
                                               unsigned long long* __restrict__ pool2m,
                                               unsigned int* __restrict__ flags2) {
    __shared__ unsigned int m_lds[5 * 84];  // rows 3ph-2..3ph+2, cols -2..81
    __shared__ int f2;

    int b = blockIdx.x;
    int third = b % 3;  b /= 3;
    int ph = b % 27;
    int t = b / 27;
    int tid = threadIdx.x;
    int ocl = tid & 63, wv = tid >> 6;
    int r0 = 3 * ph - 2;
    int pwA = third * 9, pwB = pwA + 9;

    if (tid == 0) f2 = 0;
    for (int idx = tid; idx < 420; idx += 256) {
        int r = idx / 84, col = idx % 84;
        int gr = r0 + r, gc = col - 2;
        unsigned int v = 0;
        if ((unsigned)gr < 80u && (unsigned)gc < 80u) {
            int i2 = (t * 80 + gr) * 80 + gc;
            v = mask1[i2] | (mask1[MASK_PLANE + i2] << 15);
        }
        m_lds[idx] = v;
    }
    __syncthreads();

    int oc = wv * 64 + ocl;  // 0..255; stray 250..255 reads stay within pad
    const float* wb = w2t + oc;
    bool valid = oc < 250;
    unsigned long long* prow = pool2m + ((t * 27 + ph) * 27) * 4 + wv;

#pragma unroll 1
    for (int pw = pwA; pw < pwB; ++pw) {
        int c0 = 3 * pw;  // lds col of window start (global col 3pw-2)

        unsigned int q[25];  // batched window read: 25 independent ds_reads
#pragma unroll
        for (int dr = 0; dr < 5; ++dr)
#pragma unroll
            for (int ds = 0; ds < 5; ++ds)
                q[dr * 5 + ds] = m_lds[dr * 84 + c0 + ds];

        float acc[3][3];
#pragma unroll
        for (int i = 0; i < 3; ++i)
#pragma unroll
            for (int j = 0; j < 3; ++j) acc[i][j] = 0.f;

#pragma unroll
        for (int dr = 0; dr < 5; ++dr) {
#pragma unroll
            for (int ds = 0; ds < 5; ++ds) {
                unsigned int m = q[dr * 5 + ds];
                while (m) {  // wave-uniform
                    int c1 = __builtin_ctz(m); m &= m - 1;
                    bool has2 = (m != 0);
                    int c2 = c1;
                    if (has2) { c2 = __builtin_ctz(m); m &= m - 1; }
                    const float* p1 = wb + c1 * 2250;
                    const float* p2 = wb + c2 * 2250;
                    // compile-time-valid (i,j) subset; 2 spikes' loads issue
                    // together (independent), then the adds
                    float v1[3][3], v2[3][3];
#pragma unroll
                    for (int i = 0; i < 3; ++i) {
                        if (dr - i < 0 || dr - i > 2) continue;
#pragma unroll
                        for (int j = 0; j < 3; ++j) {
                            if (ds - j < 0 || ds - j > 2) continue;
                            int off = ((dr - i) * 3 + (ds - j)) * 250;
                            v1[i][j] = p1[off];
                            v2[i][j] = p2[off];
                        }
                    }
#pragma unroll
                    for (int i = 0; i < 3; ++i) {
                        if (dr - i < 0 || dr - i > 2) continue;
#pragma unroll
                        for (int j = 0; j < 3; ++j) {
                            if (ds - j < 0 || ds - j > 2) continue;
                            acc[i][j] += v1[i][j];
                            acc[i][j] += has2 ? v2[i][j] : 0.f;
                        }
                    }
                }
            }
        }

        bool s = false;
#pragma unroll
        for (int i = 0; i < 3; ++i)
#pragma unroll
            for (int j = 0; j < 3; ++j) s = s || (acc[i][j] > 1.f);

        unsigned long long blt = __ballot(s && valid);
        if (ocl == 0) prow[pw * 4] = blt;
        if (blt) f2 = 1;  // same-value LDS store, race-safe
    }
    __syncthreads();
    if (tid == 0 && f2) flags2[t * 27 + ph] = 1u;  // multi-writer, same value
}

// ---------------- conv3(3x3) + fire(25.0) -> out [spk|pot] (20,200,29,29) x2
// block: (t, 5 oc-groups of 40, 15 row-pairs), 320 thr = 40oc x 8 col-tiles(4)
// Early-out via flags2 rows r0-2..r0+1 -> coalesced zero-fill. Dense path
// unpacks pool2m bits (never executed when pool2 is empty; kept for
// correctness on arbitrary inputs).
__global__ __launch_bounds__(320) void k_conv3(const unsigned long long* __restrict__ pool2m,
                                               const float* __restrict__ w3,
                                               float* __restrict__ out,
                                               const unsigned int* __restrict__ flags2) {
    __shared__ float w_lds[25 * 9 * 40];   // 9000 floats, [ck_local][ocl]
    __shared__ float in_lds[25 * 4 * 34];  // 3400 floats, [cl][r][col]

    int b = blockIdx.x;
    int rb = b % 15;  b /= 15;
    int ocg = b % 5;  b /= 5;
    int t = b;
    int oc0 = ocg * 40;
    int r0 = 2 * rb;  // output rows r0, r0+1
    int tid = threadIdx.x;
    int ocl = tid % 40, ct = tid / 40;  // ct in [0,8)

    // receptive field: pool2 rows r0-2..r0+1
    {
        unsigned int f = 0;
        int rlo = r0 - 2; if (rlo < 0) rlo = 0;
        int rhi = r0 + 1; if (rhi > 26) rhi = 26;
        for (int r = rlo; r <= rhi; ++r) f |= flags2[t * 27 + r];
        if (f == 0) {
            // exact zeros, coalesced: rows r0..r0+nrows-1, all 29 cols, 40 ocs
            int nrows = (r0 + 1 < 29) ? 2 : 1;
            int stride = 29 * nrows;
            int cnt = 40 * stride;
            for (int idx = tid; idx < cnt; idx += 320) {
                int o = idx / stride, rem = idx % stride;
                size_t base = (size_t)((t * 200 + oc0 + o) * 29 + r0) * 29 + rem;
                out[base] = 0.f;
                out[OUT_HALF + base] = 0.f;
            }
            return;
        }
    }

    float acc[2][4];
#pragma unroll
    for (int i = 0; i < 2; ++i)
#pragma unroll
        for (int j = 0; j < 4; ++j) acc[i][j] = 0.f;

    for (int chn = 0; chn < 10; ++chn) {  // channel chunks of 25
        int cc0 = chn * 25;
        for (int idx = tid; idx < 25 * 9 * 40; idx += 320) {
            int o = idx % 40, ck = idx / 40;         // ck in [0,225)
            int ckg = cc0 * 9 + ck;                  // global (c,kh,kw) index
            w_lds[idx] = w3[(size_t)(oc0 + o) * 2250 + ckg];
        }
        for (int idx = tid; idx < 25 * 4 * 34; idx += 320) {
            int col = idx % 34;
            int rem = idx / 34;
            int r = rem & 3, cl = rem >> 2;
            int gr = r0 + r - 2, gc = col - 2;
            float v = 0.f;
            if ((unsigned)gr < 27u && (unsigned)gc < 27u) {
                int c = cc0 + cl;
                unsigned long long wbits =
                    pool2m[((t * 27 + gr) * 27 + gc) * 4 + (c >> 6)];
                v = (float)((wbits >> (c & 63)) & 1ull);
            }
            in_lds[idx] = v;
        }
        __syncthreads();

        for (int cl = 0; cl < 25; ++cl) {
            float in[4][6];
#pragma unroll
            for (int r = 0; r < 4; ++r)
#pragma unroll
                for (int j = 0; j < 6; ++j)
                    in[r][j] = in_lds[(cl * 4 + r) * 34 + ct * 4 + j];
            const float* wp = &w_lds[cl * 360 + ocl];
#pragma unroll
            for (int k = 0; k < 9; ++k) {
                float w = wp[k * 40];
                int kh = k / 3, kw = k % 3;
#pragma unroll
                for (int i = 0; i < 2; ++i)
#pragma unroll
                    for (int j = 0; j < 4; ++j)
                        acc[i][j] += in[i + kh][j + kw] * w;
            }
        }
        __syncthreads();
    }

    {
        int oc = oc0 + ocl;  // always < 200
#pragma unroll
        for (int i = 0; i < 2; ++i) {
            int r = r0 + i;
            if (r < 29) {
#pragma unroll
                for (int j = 0; j < 4; ++j) {
                    int col = ct * 4 + j;
                    if (col < 29) {
                        float pot = acc[i][j];
                        bool s = pot > 25.f;
                        size_t base = ((size_t)((t * 200 + oc) * 29 + r)) * 29 + col;
                        out[base] = s ? 1.f : 0.f;
                        out[OUT_HALF + base] = s ? pot : 0.f;
                    }
                }
            }
        }
    }
}

extern "C" void kernel_launch(void* const* d_in, const int* in_sizes, int n_in,
                              void* d_out, int out_size, void* d_ws, size_t ws_size,
                              hipStream_t stream) {
    const float* x  = (const float*)d_in[0];
    const float* w1 = (const float*)d_in[1];
    const float* w2 = (const float*)d_in[2];
    const float* w3 = (const float*)d_in[3];
    float* out = (float*)d_out;

    // workspace layout (bytes):
    //   mask1  u32: [0, 1,024,000)           2 planes x 20*80*80
    //   pool2m u64: [1,024,000, 1,490,560)   20*27*27*4 x 8B ballot words
    //   w2t    f32: [1,490,560, 1,760,560)   270x250
    //   pad       : [1,760,560, 1,764,672)   absorbs conv2 stray oc reads
    //   flags2    : [1,764,672, +2,160)      u32[20*27]
    unsigned int* mask1 = (unsigned int*)d_ws;
    unsigned long long* pool2m = (unsigned long long*)((char*)d_ws + 1024000);
    float* w2t = (float*)((char*)d_ws + 1490560);
    unsigned int* flags2 = (unsigned int*)((char*)d_ws + 1764672);

    // blocks 0..999: conv1; blocks 1000..1263: w2 transpose + flags2 zero
    k_conv1<<<1264, 256, 0, stream>>>(x, w1, w2, w2t, mask1, flags2);
    k_conv2<<<20 * 27 * 3, 256, 0, stream>>>(mask1, w2t, pool2m, flags2);
    k_conv3<<<20 * 5 * 15, 320, 0, stream>>>(pool2m, w3, out, flags2);
}

// Round 9
// 150.441 us; speedup vs baseline: 1.2748x; 1.0073x over previous
//
#include <hip/hip_runtime.h>

// deepSNN forward, layer_idx=3 path, fp32 exact, element-sparse conv2.
// x:(20,6,160,160) w1:(30,6,4,4) w2:(250,30,3,3) w3:(200,250,3,3)
// pipeline: pad2->conv1->fire(1)->pool2x2 -> pad2->conv2->fire(1)->pool3x3
//           -> pad2->conv3->fire(25) -> out = [spk | pot] (2 x 20*200*29*29 fp32)
//
// r8 post-mortem: budget accounting (dispatch sums matched totals in r1) shows
// conv3's zero-fill was ~50-65us all along: scalar dword stores in unaligned
// 232B chunks -> partial-line HBM writes -> L2 read-modify-write doubles
// traffic (same pathology as r6's conv2). r9: per-t fast path — when all 27
// row flags of t are clear, the t-image of out is one contiguous float4-
// aligned region; 75 blocks memset it with dwordx4 full-line stores. General
// per-row path kept for arbitrary inputs. conv1/conv2 untouched.

#define OUT_HALF 3364000  // 20*200*29*29
#define MASK_PLANE 128000 // 20*80*80
#define T_FLOATS 168200   // 200*29*29 floats per t per half

typedef float v2f __attribute__((ext_vector_type(2)));

// ---------------- conv1(4x4)+fire(1)+pool2x2 -> mask1 (blocks 0..999)
//                  + w2 transpose + flags2 zero   (blocks 1000..1263)
// conv1 block: (t, 5 row-tiles, 5 col-tiles, 2 oc-halves), 256 thr.
// mask1[h*MASK_PLANE + (t*80+r)*80+c] bits 0..14 = spikes of oc h*15..h*15+14.
// Input LDS layout: [c][row][perm(col)], perm = col/2 + (col&1)*18 -> window
// reads hit 2 lanes/bank (free). Weights: wave-uniform global float4 loads.
__global__ __launch_bounds__(256, 3) void k_conv1(const float* __restrict__ x,
                                                  const float* __restrict__ w1,
                                                  const float* __restrict__ w2,
                                                  float* __restrict__ w2t,
                                                  unsigned int* __restrict__ mask1,
                                                  unsigned int* __restrict__ flags2) {
    if (blockIdx.x >= 1000) {  // transpose part: w2[oc][ck] -> w2t[ck][oc]
        int tb = blockIdx.x - 1000;
        int tid = threadIdx.x;
        if (tb == 0)
            for (int i = tid; i < 540; i += 256) flags2[i] = 0u;
        int idx = tb * 256 + tid;
        if (idx < 67500) {
            int oc = idx / 270, ck = idx % 270;
            w2t[ck * 250 + oc] = w2[idx];
        }
        return;
    }

    __shared__ float in_lds[6 * 35 * 36];  // 30240 B

    int b = blockIdx.x;
    int h = b & 1;     b >>= 1;  // oc half: 0 -> oc 0..14, 1 -> oc 15..29
    int colt = b % 5;  b /= 5;
    int rowt = b % 5;  b /= 5;
    int t = b;
    int ph0 = rowt * 16, pw0 = colt * 16;
    int i0 = 2 * ph0, j0 = 2 * pw0;  // padded-164 coords of tile conv origin
    int tid = threadIdx.x;

    for (int idx = tid; idx < 6 * 35 * 35; idx += 256) {
        int c = idx / 1225;
        int rem = idx % 1225;
        int r = rem / 35, col = rem % 35;
        int gr = i0 + r - 2, gc = j0 + col - 2;
        float v = 0.f;
        if ((unsigned)gr < 160u && (unsigned)gc < 160u)
            v = x[((t * 6 + c) * 160 + gr) * 160 + gc];
        in_lds[c * 1260 + r * 36 + (col >> 1) + (col & 1) * 18] = v;
    }
    __syncthreads();

    int pw_l = tid & 15, ph_l = tid >> 4;
    int rb = 2 * ph_l;

    v2f acc01[15], acc23[15];  // positions (0,0),(0,1) and (1,0),(1,1)
#pragma unroll
    for (int o = 0; o < 15; ++o) {
        acc01[o] = (v2f)(0.f);
        acc23[o] = (v2f)(0.f);
    }

    // weights for this half: w1[(h*15+o)][c][kh][kw], float4 per (o,c,kh)
    const float4* wq = (const float4*)w1 + h * 15 * 24;

#pragma unroll 1
    for (int c = 0; c < 6; ++c) {
        // window cols cb..cb+4 (cb=2*pw_l): permuted offsets 0,18,1,19,2
        const float* pl = &in_lds[c * 1260 + rb * 36 + pw_l];
        float q[5][5];
#pragma unroll
        for (int r = 0; r < 5; ++r) {
            const float* pr = pl + r * 36;
            q[r][0] = pr[0];  q[r][1] = pr[18]; q[r][2] = pr[1];
            q[r][3] = pr[19]; q[r][4] = pr[2];
        }
        v2f p[5][4];  // p[r][k] = {in[r][k], in[r][k+1]}
#pragma unroll
        for (int r = 0; r < 5; ++r)
#pragma unroll
            for (int k = 0; k < 4; ++k) {
                p[r][k].x = q[r][k];
                p[r][k].y = q[r][k + 1];
            }
#pragma unroll
        for (int o = 0; o < 15; ++o) {
            const float4* wp = wq + o * 24 + c * 4;
#pragma unroll
            for (int kh = 0; kh < 4; ++kh) {
                float4 wv = wp[kh];  // uniform -> scalar regs
                v2f w0 = {wv.x, wv.x}, w1v = {wv.y, wv.y};
                v2f w2v = {wv.z, wv.z}, w3v = {wv.w, wv.w};
                acc01[o] += p[kh][0] * w0;   acc23[o] += p[kh + 1][0] * w0;
                acc01[o] += p[kh][1] * w1v;  acc23[o] += p[kh + 1][1] * w1v;
                acc01[o] += p[kh][2] * w2v;  acc23[o] += p[kh + 1][2] * w2v;
                acc01[o] += p[kh][3] * w3v;  acc23[o] += p[kh + 1][3] * w3v;
            }
        }
    }

    unsigned int msk = 0;
#pragma unroll
    for (int o = 0; o < 15; ++o) {
        bool s = acc01[o].x > 1.f || acc01[o].y > 1.f ||
                 acc23[o].x > 1.f || acc23[o].y > 1.f;
        if (s) msk |= 1u << o;
    }
    mask1[h * MASK_PLANE + (t * 80 + ph0 + ph_l) * 80 + pw0 + pw_l] = msk;
}

// ---------------- sparse conv2(3x3) + fire(1.0) + pool3x3 -> pool2m ballot
// block: (t, ph, 3 pw-thirds) = 1620 blocks, 256 thr = 4 waves; wave w owns
// ocs w*64..+63. Stage 5x84 mask band; per pw: 25 window words batched into
// registers (independent ds_reads), spikes processed two-at-a-time with 18
// independent weight loads per group. Output: __ballot u64 per (pw,wave).
__global__ __launch_bounds__(256) void k_conv2(const unsigned int* __restrict__ mask1,
                                               const float* __restrict__ w2t,
                                               unsigned long long* __restrict__ pool2m,
                                               unsigned int* __restrict__ flags2) {
    __shared__ unsigned int m_lds[5 * 84];  // rows 3ph-2..3ph+2, cols -2..81
    __shared__ int f2;

    int b = blockIdx.x;
    int third = b % 3;  b /= 3;
    int ph = b % 27;
    int t = b / 27;
    int tid = threadIdx.x;
    int ocl = tid & 63, wv = tid >> 6;
    int r0 = 3 * ph - 2;
    int pwA = third * 9, pwB = pwA + 9;

    if (tid == 0) f2 = 0;
    for (int idx = tid; idx < 420; idx += 256) {
        int r = idx / 84, col = idx % 84;
        int gr = r0 + r, gc = col - 2;
        unsigned int v = 0;
        if ((unsigned)gr < 80u && (unsigned)gc < 80u) {
            int i2 = (t * 80 + gr) * 80 + gc;
            v = mask1[i2] | (mask1[MASK_PLANE + i2] << 15);
        }
        m_lds[idx] = v;
    }
    __syncthreads();

    int oc = wv * 64 + ocl;  // 0..255; stray 250..255 reads stay within pad
    const float* wb = w2t + oc;
    bool valid = oc < 250;
    unsigned long long* prow = pool2m + ((t * 27 + ph) * 27) * 4 + wv;

#pragma unroll 1
    for (int pw = pwA; pw < pwB; ++pw) {
        int c0 = 3 * pw;  // lds col of window start (global col 3pw-2)

        unsigned int q[25];  // batched window read: 25 independent ds_reads
#pragma unroll
        for (int dr = 0; dr < 5; ++dr)
#pragma unroll
            for (int ds = 0; ds < 5; ++ds)
                q[dr * 5 + ds] = m_lds[dr * 84 + c0 + ds];

        float acc[3][3];
#pragma unroll
        for (int i = 0; i < 3; ++i)
#pragma unroll
            for (int j = 0; j < 3; ++j) acc[i][j] = 0.f;

#pragma unroll
        for (int dr = 0; dr < 5; ++dr) {
#pragma unroll
            for (int ds = 0; ds < 5; ++ds) {
                unsigned int m = q[dr * 5 + ds];
                while (m) {  // wave-uniform
                    int c1 = __builtin_ctz(m); m &= m - 1;
                    bool has2 = (m != 0);
                    int c2 = c1;
                    if (has2) { c2 = __builtin_ctz(m); m &= m - 1; }
                    const float* p1 = wb + c1 * 2250;
                    const float* p2 = wb + c2 * 2250;
                    // compile-time-valid (i,j) subset; 2 spikes' loads issue
                    // together (independent), then the adds
                    float v1[3][3], v2[3][3];
#pragma unroll
                    for (int i = 0; i < 3; ++i) {
                        if (dr - i < 0 || dr - i > 2) continue;
#pragma unroll
                        for (int j = 0; j < 3; ++j) {
                            if (ds - j < 0 || ds - j > 2) continue;
                            int off = ((dr - i) * 3 + (ds - j)) * 250;
                            v1[i][j] = p1[off];
                            v2[i][j] = p2[off];
                        }
                    }
#pragma unroll
                    for (int i = 0; i < 3; ++i) {
                        if (dr - i < 0 || dr - i > 2) continue;
#pragma unroll
                        for (int j = 0; j < 3; ++j) {
                            if (ds - j < 0 || ds - j > 2) continue;
                            acc[i][j] += v1[i][j];
                            acc[i][j] += has2 ? v2[i][j] : 0.f;
                        }
                    }
                }
            }
        }

        bool s = false;
#pragma unroll
        for (int i = 0; i < 3; ++i)
#pragma unroll
            for (int j = 0; j < 3; ++j) s = s || (acc[i][j] > 1.f);

        unsigned long long blt = __ballot(s && valid);
        if (ocl == 0) prow[pw * 4] = blt;
        if (blt) f2 = 1;  // same-value LDS store, race-safe
    }
    __syncthreads();
    if (tid == 0 && f2) flags2[t * 27 + ph] = 1u;  // multi-writer, same value
}

// ---------------- conv3(3x3) + fire(25.0) -> out [spk|pot] (20,200,29,29) x2
// block: (t, 5 oc-groups of 40, 15 row-pairs), 320 thr = 40oc x 8 col-tiles(4)
// Fast path: all 27 flags of t clear -> whole t-image is zero; the 75 blocks
// of this t memset contiguous float4 slices (full-line stores, no RMW).
// Row-pair early-out and dense path kept for arbitrary inputs.
__global__ __launch_bounds__(320) void k_conv3(const unsigned long long* __restrict__ pool2m,
                                               const float* __restrict__ w3,
                                               float* __restrict__ out,
                                               const unsigned int* __restrict__ flags2) {
    __shared__ float w_lds[25 * 9 * 40];   // 9000 floats, [ck_local][ocl]
    __shared__ float in_lds[25 * 4 * 34];  // 3400 floats, [cl][r][col]

    int b = blockIdx.x;
    int rb = b % 15;  b /= 15;
    int ocg = b % 5;  b /= 5;
    int t = b;
    int oc0 = ocg * 40;
    int r0 = 2 * rb;  // output rows r0, r0+1
    int tid = threadIdx.x;
    int ocl = tid % 40, ct = tid / 40;  // ct in [0,8)

    // whole-t union of flags (wave-uniform scalar loads)
    {
        unsigned int fT = 0;
        const unsigned int* fp = flags2 + t * 27;
#pragma unroll
        for (int r = 0; r < 27; ++r) fT |= fp[r];
        if (fT == 0) {
            // whole t-image zero: contiguous float4 memset, 75 blocks share.
            // per half: 200*841 = 168200 floats = 42050 float4 (16B-aligned).
            float4 z; z.x = 0.f; z.y = 0.f; z.z = 0.f; z.w = 0.f;
            float4* o0 = (float4*)(out + (size_t)t * T_FLOATS);
            float4* o1 = (float4*)(out + OUT_HALF + (size_t)t * T_FLOATS);
            int s = ocg * 15 + rb;           // slice id 0..74
            int lo = s * 561;                // 75*561 = 42075 >= 42050
            int hi = lo + 561; if (hi > 42050) hi = 42050;
            for (int i = lo + tid; i < hi; i += 320) {
                o0[i] = z;
                o1[i] = z;
            }
            return;
        }
    }

    // receptive field: pool2 rows r0-2..r0+1
    {
        unsigned int f = 0;
        int rlo = r0 - 2; if (rlo < 0) rlo = 0;
        int rhi = r0 + 1; if (rhi > 26) rhi = 26;
        for (int r = rlo; r <= rhi; ++r) f |= flags2[t * 27 + r];
        if (f == 0) {
            // exact zeros, rows r0..r0+nrows-1, all 29 cols, 40 ocs
            int nrows = (r0 + 1 < 29) ? 2 : 1;
            int stride = 29 * nrows;
            int cnt = 40 * stride;
            for (int idx = tid; idx < cnt; idx += 320) {
                int o = idx / stride, rem = idx % stride;
                size_t base = (size_t)((t * 200 + oc0 + o) * 29 + r0) * 29 + rem;
                out[base] = 0.f;
                out[OUT_HALF + base] = 0.f;
            }
            return;
        }
    }

    float acc[2][4];
#pragma unroll
    for (int i = 0; i < 2; ++i)
#pragma unroll
        for (int j = 0; j < 4; ++j) acc[i][j] = 0.f;

    for (int chn = 0; chn < 10; ++chn) {  // channel chunks of 25
        int cc0 = chn * 25;
        for (int idx = tid; idx < 25 * 9 * 40; idx += 320) {
            int o = idx % 40, ck = idx / 40;         // ck in [0,225)
            int ckg = cc0 * 9 + ck;                  // global (c,kh,kw) index
            w_lds[idx] = w3[(size_t)(oc0 + o) * 2250 + ckg];
        }
        for (int idx = tid; idx < 25 * 4 * 34; idx += 320) {
            int col = idx % 34;
            int rem = idx / 34;
            int r = rem & 3, cl = rem >> 2;
            int gr = r0 + r - 2, gc = col - 2;
            float v = 0.f;
            if ((unsigned)gr < 27u && (unsigned)gc < 27u) {
                int c = cc0 + cl;
                unsigned long long wbits =
                    pool2m[((t * 27 + gr) * 27 + gc) * 4 + (c >> 6)];
                v = (float)((wbits >> (c & 63)) & 1ull);
            }
            in_lds[idx] = v;
        }
        __syncthreads();

        for (int cl = 0; cl < 25; ++cl) {
            float in[4][6];
#pragma unroll
            for (int r = 0; r < 4; ++r)
#pragma unroll
                for (int j = 0; j < 6; ++j)
                    in[r][j] = in_lds[(cl * 4 + r) * 34 + ct * 4 + j];
            const float* wp = &w_lds[cl * 360 + ocl];
#pragma unroll
            for (int k = 0; k < 9; ++k) {
                float w = wp[k * 40];
                int kh = k / 3, kw = k % 3;
#pragma unroll
                for (int i = 0; i < 2; ++i)
#pragma unroll
                    for (int j = 0; j < 4; ++j)
                        acc[i][j] += in[i + kh][j + kw] * w;
            }
        }
        __syncthreads();
    }

    {
        int oc = oc0 + ocl;  // always < 200
#pragma unroll
        for (int i = 0; i < 2; ++i) {
            int r = r0 + i;
            if (r < 29) {
#pragma unroll
                for (int j = 0; j < 4; ++j) {
                    int col = ct * 4 + j;
                    if (col < 29) {
                        float pot = acc[i][j];
                        bool s = pot > 25.f;
                        size_t base = ((size_t)((t * 200 + oc) * 29 + r)) * 29 + col;
                        out[base] = s ? 1.f : 0.f;
                        out[OUT_HALF + base] = s ? pot : 0.f;
                    }
                }
            }
        }
    }
}

extern "C" void kernel_launch(void* const* d_in, const int* in_sizes, int n_in,
                              void* d_out, int out_size, void* d_ws, size_t ws_size,
                              hipStream_t stream) {
    const float* x  = (const float*)d_in[0];
    const float* w1 = (const float*)d_in[1];
    const float* w2 = (const float*)d_in[2];
    const float* w3 = (const float*)d_in[3];
    float* out = (float*)d_out;

    // workspace layout (bytes):
    //   mask1  u32: [0, 1,024,000)           2 planes x 20*80*80
    //   pool2m u64: [1,024,000, 1,490,560)   20*27*27*4 x 8B ballot words
    //   w2t    f32: [1,490,560, 1,760,560)   270x250
    //   pad       : [1,760,560, 1,764,672)   absorbs conv2 stray oc reads
    //   flags2    : [1,764,672, +2,160)      u32[20*27]
    unsigned int* mask1 = (unsigned int*)d_ws;
    unsigned long long* pool2m = (unsigned long long*)((char*)d_ws + 1024000);
    float* w2t = (float*)((char*)d_ws + 1490560);
    unsigned int* flags2 = (unsigned int*)((char*)d_ws + 1764672);

    // blocks 0..999: conv1; blocks 1000..1263: w2 transpose + flags2 zero
    k_conv1<<<1264, 256, 0, stream>>>(x, w1, w2, w2t, mask1, flags2);
    k_conv2<<<20 * 27 * 3, 256, 0, stream>>>(mask1, w2t, pool2m, flags2);
    k_conv3<<<20 * 5 * 15, 320, 0, stream>>>(pool2m, w3, out, flags2);
}